// Round 11
// baseline (161.972 us; speedup 1.0000x reference)
//
#include <hip/hip_runtime.h>
#include <math.h>

#define EMBED 768
#define HEADS 12
#define HDIM 64
#define BATCH 2
#define SEQ 2048
#define MTOT (BATCH*SEQ)   // 4096

typedef short s8v __attribute__((ext_vector_type(8)));
typedef short s4v __attribute__((ext_vector_type(4)));
typedef float f4v __attribute__((ext_vector_type(4)));

__device__ __forceinline__ short f2bf(float f) {
    union { float f; unsigned u; } v; v.f = f;
    unsigned r = v.u + 0x7FFFu + ((v.u >> 16) & 1u);
    return (short)(r >> 16);
}

// pack two floats -> two bf16 in one dword (manual; used in GEMM epilogue)
__device__ __forceinline__ unsigned pk2bf(float a, float b) {
    union { float f; unsigned u; } x, y; x.f = a; y.f = b;
    return ((y.u + 0x8000u) & 0xFFFF0000u) | ((x.u + 0x8000u) >> 16);
}

// HW packed convert: D.lo = bf16(a), D.hi = bf16(b), RNE
__device__ __forceinline__ unsigned cvtpk(float a, float b) {
    unsigned r;
    asm("v_cvt_pk_bf16_f32 %0, %1, %2" : "=v"(r) : "v"(a), "v"(b));
    return r;
}

__device__ __forceinline__ float fexp2(float x) {
#if __has_builtin(__builtin_amdgcn_exp2f)
    return __builtin_amdgcn_exp2f(x);
#else
    return exp2f(x);
#endif
}

// async global->LDS, 16B/lane; lds base wave-uniform, lane scatter on GLOBAL side ok
__device__ __forceinline__ void gll16(const short* g, short* l) {
    __builtin_amdgcn_global_load_lds((const __attribute__((address_space(1))) void*)g,
                                     (__attribute__((address_space(3))) void*)l, 16, 0, 0);
}

// ---------------- fp32 -> bf16 converts ----------------
__global__ __launch_bounds__(256) void cvt_all(
        const float* __restrict__ x,  const float* __restrict__ wq,
        const float* __restrict__ wk, const float* __restrict__ wv,
        const float* __restrict__ wo,
        short* __restrict__ xb, short* __restrict__ wqb, short* __restrict__ wkb,
        short* __restrict__ wvb, short* __restrict__ wob) {
    const int seg = blockIdx.y;
    const float* src; short* dst; int n4;
    if      (seg == 0) { src = x;  dst = xb;  n4 = MTOT * EMBED / 4; }
    else if (seg == 1) { src = wq; dst = wqb; n4 = EMBED * EMBED / 4; }
    else if (seg == 2) { src = wk; dst = wkb; n4 = EMBED * EMBED / 4; }
    else if (seg == 3) { src = wv; dst = wvb; n4 = EMBED * EMBED / 4; }
    else               { src = wo; dst = wob; n4 = EMBED * EMBED / 4; }
    for (int i = blockIdx.x * 256 + threadIdx.x; i < n4; i += gridDim.x * 256) {
        float4 f = ((const float4*)src)[i];
        short4 o;
        o.x = f2bf(f.x); o.y = f2bf(f.y); o.z = f2bf(f.z); o.w = f2bf(f.w);
        ((short4*)dst)[i] = o;
    }
}

// ---------------- fused QKV GEMM (BM=128, BN=128, BK=32, 3-buf 2-ahead counted) -----
// C[m][n] = sum_k A[m][k]*W[n][k] + bias[n]
// mode(z): 0->Q [b,h,s,d] pre-scaled by 0.125*log2(e), 1->K [b,h,s,d], 2->V [b,h,d,s]
// r8's BK=64 proved GEMM time is drain-bound (halving drains = -9us). This removes
// the remaining full drains entirely with the r9-PROVEN 3-buffer counted scheme:
// issue tile t+2's 4-load group during iter t; barrier waits vmcnt(4) (keeps the
// just-issued group in flight; the group needed next was issued a full iter earlier
// and is retired by oldest-first vmcnt semantics). Fragment math = r0-proven BK=32
// (64B rows, 2-way bank aliasing = free). No inline-asm in the compute chain.
// LDS: 3 x (8+8) KB = 48 KB -> 3 blocks/CU >= grid's 2.25 avg (all resident).
__global__ __launch_bounds__(256, 3) void gemm_qkv(const short* __restrict__ A,
        const short* __restrict__ Wq, const short* __restrict__ Wk, const short* __restrict__ Wv,
        const float* __restrict__ bq, const float* __restrict__ bk, const float* __restrict__ bv,
        short* __restrict__ Qo, short* __restrict__ Ko, short* __restrict__ Vo) {
    const int mode = blockIdx.z;
    const short* W    = (mode == 0) ? Wq : (mode == 1) ? Wk : Wv;
    const float* bias = (mode == 0) ? bq : (mode == 1) ? bk : bv;
    // fold softmax scale (1/8) and log2(e) into Q so flash needs no fmaf on scores
    const float qs = (mode == 0) ? (0.125f * 1.44269504f) : 1.0f;

    __shared__ short As[3][128 * 32];   // 24 KB
    __shared__ short Ws[3][128 * 32];   // 24 KB

    const int tid = threadIdx.x;
    const int lane = tid & 63, wid = tid >> 6;
    const int quad = lane >> 4, lr = lane & 15;
    const int m0 = blockIdx.x * 128, n0 = blockIdx.y * 128;
    const int wm = (wid >> 1) * 64, wn = (wid & 1) * 64;
    const int ar = lane >> 2, ac = (lane & 3) * 8;

    f4v acc[4][4];
    for (int a = 0; a < 4; a++)
        for (int b = 0; b < 4; b++)
            for (int i = 0; i < 4; i++) acc[a][b][i] = 0.f;

    // prologue: tile 0 -> buf 0, tile 1 -> buf 1 (groups pinned in order), wait for
    // tile 0 only (vmcnt(4): tile 1's 4 loads stay in flight).
    gll16(&A[(long)(m0 + wid * 32 + ar) * EMBED + ac],      &As[0][(wid * 32) * 32]);
    gll16(&A[(long)(m0 + wid * 32 + 16 + ar) * EMBED + ac], &As[0][(wid * 32 + 16) * 32]);
    gll16(&W[(long)(n0 + wid * 32 + ar) * EMBED + ac],      &Ws[0][(wid * 32) * 32]);
    gll16(&W[(long)(n0 + wid * 32 + 16 + ar) * EMBED + ac], &Ws[0][(wid * 32 + 16) * 32]);
    __builtin_amdgcn_sched_barrier(0);
    gll16(&A[(long)(m0 + wid * 32 + ar) * EMBED + 32 + ac],      &As[1][(wid * 32) * 32]);
    gll16(&A[(long)(m0 + wid * 32 + 16 + ar) * EMBED + 32 + ac], &As[1][(wid * 32 + 16) * 32]);
    gll16(&W[(long)(n0 + wid * 32 + ar) * EMBED + 32 + ac],      &Ws[1][(wid * 32) * 32]);
    gll16(&W[(long)(n0 + wid * 32 + 16 + ar) * EMBED + 32 + ac], &Ws[1][(wid * 32 + 16) * 32]);
    __builtin_amdgcn_sched_barrier(0);
    asm volatile("s_waitcnt vmcnt(4)" ::: "memory");
    __builtin_amdgcn_s_barrier();
    __builtin_amdgcn_sched_barrier(0);

    int cur = 0;
    for (int t = 0; t < 24; t++) {
        // ---- issue tile t+2's 4-load group into buffer (cur+2)%3 ----
        if (t < 22) {
            const int nx = (cur >= 1) ? (cur - 1) : 2;   // (cur+2)%3
            const int kn = (t + 2) * 32;
            gll16(&A[(long)(m0 + wid * 32 + ar) * EMBED + kn + ac],      &As[nx][(wid * 32) * 32]);
            gll16(&A[(long)(m0 + wid * 32 + 16 + ar) * EMBED + kn + ac], &As[nx][(wid * 32 + 16) * 32]);
            gll16(&W[(long)(n0 + wid * 32 + ar) * EMBED + kn + ac],      &Ws[nx][(wid * 32) * 32]);
            gll16(&W[(long)(n0 + wid * 32 + 16 + ar) * EMBED + kn + ac], &Ws[nx][(wid * 32 + 16) * 32]);
        }
        __builtin_amdgcn_sched_barrier(0);   // keep issue above compute

        s8v af[4], bf[4];
#pragma unroll
        for (int mi = 0; mi < 4; mi++)
            af[mi] = *(const s8v*)&As[cur][(wm + mi * 16 + lr) * 32 + quad * 8];
#pragma unroll
        for (int ni = 0; ni < 4; ni++)
            bf[ni] = *(const s8v*)&Ws[cur][(wn + ni * 16 + lr) * 32 + quad * 8];
#pragma unroll
        for (int mi = 0; mi < 4; mi++)
#pragma unroll
            for (int ni = 0; ni < 4; ni++)
                acc[mi][ni] = __builtin_amdgcn_mfma_f32_16x16x32_bf16(af[mi], bf[ni], acc[mi][ni], 0, 0, 0);

        // ---- counted barrier: tile t+1's group (issued iter t-1) retired; the group
        // just issued (t+2) stays in flight. Tail iters drain fully. ----
        if (t < 22) { asm volatile("s_waitcnt vmcnt(4)" ::: "memory"); }
        else        { asm volatile("s_waitcnt vmcnt(0)" ::: "memory"); }
        __builtin_amdgcn_s_barrier();
        __builtin_amdgcn_sched_barrier(0);
        cur = (cur == 2) ? 0 : cur + 1;
    }

    if (mode == 2) {
        for (int mi = 0; mi < 4; mi++) {
            int srow2 = m0 + wm + mi * 16 + quad * 4;
            int b = srow2 >> 11, s = srow2 & 2047;
            for (int ni = 0; ni < 4; ni++) {
                int n = n0 + wn + ni * 16 + lr;
                int h = n >> 6, d = n & 63;
                float bb = bias[n];
                uint2 pk;
                pk.x = pk2bf(acc[mi][ni][0] + bb, acc[mi][ni][1] + bb);
                pk.y = pk2bf(acc[mi][ni][2] + bb, acc[mi][ni][3] + bb);
                *(uint2*)&Vo[(((long)(b * HEADS + h) * HDIM + d) * SEQ) + s] = pk;
            }
        }
    } else {
        short* Out = (mode == 0) ? Qo : Ko;
        for (int mi = 0; mi < 4; mi++) {
            for (int ni = 0; ni < 4; ni++) {
                int n = n0 + wn + ni * 16 + lr;
                int h = n >> 6, d = n & 63;
                float bb = bias[n];
                for (int i = 0; i < 4; i++) {
                    int m = m0 + wm + mi * 16 + quad * 4 + i;
                    int b = m >> 11, s = m & 2047;
                    Out[(((long)(b * HEADS + h) * SEQ + s) * HDIM) + d] =
                        f2bf((acc[mi][ni][i] + bb) * qs);
                }
            }
        }
    }
}

// ---------------- output projection GEMM (BM=128, BN=64, BK=32, 3-buf counted) ------
__global__ __launch_bounds__(256, 4) void gemm_out(const short* __restrict__ A,
        const short* __restrict__ W, const float* __restrict__ bias,
        float* __restrict__ Out) {
    __shared__ short As[3][128 * 32];   // 24 KB
    __shared__ short Ws[3][64 * 32];    // 12 KB

    const int tid = threadIdx.x;
    const int lane = tid & 63, wid = tid >> 6;
    const int quad = lane >> 4, lr = lane & 15;
    const int m0 = blockIdx.x * 128, n0 = blockIdx.y * 64;
    const int wm = (wid >> 1) * 64, wn = (wid & 1) * 32;
    const int ar = lane >> 2, ac = (lane & 3) * 8;

    f4v acc[4][2];
    for (int a = 0; a < 4; a++)
        for (int b = 0; b < 2; b++)
            for (int i = 0; i < 4; i++) acc[a][b][i] = 0.f;

    // prologue: tiles 0,1 -> bufs 0,1; wait tile 0 only (vmcnt(3))
    gll16(&A[(long)(m0 + wid * 32 + ar) * EMBED + ac],      &As[0][(wid * 32) * 32]);
    gll16(&A[(long)(m0 + wid * 32 + 16 + ar) * EMBED + ac], &As[0][(wid * 32 + 16) * 32]);
    gll16(&W[(long)(n0 + wid * 16 + ar) * EMBED + ac],      &Ws[0][(wid * 16) * 32]);
    __builtin_amdgcn_sched_barrier(0);
    gll16(&A[(long)(m0 + wid * 32 + ar) * EMBED + 32 + ac],      &As[1][(wid * 32) * 32]);
    gll16(&A[(long)(m0 + wid * 32 + 16 + ar) * EMBED + 32 + ac], &As[1][(wid * 32 + 16) * 32]);
    gll16(&W[(long)(n0 + wid * 16 + ar) * EMBED + 32 + ac],      &Ws[1][(wid * 16) * 32]);
    __builtin_amdgcn_sched_barrier(0);
    asm volatile("s_waitcnt vmcnt(3)" ::: "memory");
    __builtin_amdgcn_s_barrier();
    __builtin_amdgcn_sched_barrier(0);

    int cur = 0;
    for (int t = 0; t < 24; t++) {
        if (t < 22) {
            const int nx = (cur >= 1) ? (cur - 1) : 2;   // (cur+2)%3
            const int kn = (t + 2) * 32;
            gll16(&A[(long)(m0 + wid * 32 + ar) * EMBED + kn + ac],      &As[nx][(wid * 32) * 32]);
            gll16(&A[(long)(m0 + wid * 32 + 16 + ar) * EMBED + kn + ac], &As[nx][(wid * 32 + 16) * 32]);
            gll16(&W[(long)(n0 + wid * 16 + ar) * EMBED + kn + ac],      &Ws[nx][(wid * 16) * 32]);
        }
        __builtin_amdgcn_sched_barrier(0);

        s8v af[4], bf[2];
#pragma unroll
        for (int mi = 0; mi < 4; mi++)
            af[mi] = *(const s8v*)&As[cur][(wm + mi * 16 + lr) * 32 + quad * 8];
#pragma unroll
        for (int ni = 0; ni < 2; ni++)
            bf[ni] = *(const s8v*)&Ws[cur][(wn + ni * 16 + lr) * 32 + quad * 8];
#pragma unroll
        for (int mi = 0; mi < 4; mi++)
#pragma unroll
            for (int ni = 0; ni < 2; ni++)
                acc[mi][ni] = __builtin_amdgcn_mfma_f32_16x16x32_bf16(af[mi], bf[ni], acc[mi][ni], 0, 0, 0);

        if (t < 22) { asm volatile("s_waitcnt vmcnt(3)" ::: "memory"); }
        else        { asm volatile("s_waitcnt vmcnt(0)" ::: "memory"); }
        __builtin_amdgcn_s_barrier();
        __builtin_amdgcn_sched_barrier(0);
        cur = (cur == 2) ? 0 : cur + 1;
    }

    for (int mi = 0; mi < 4; mi++)
        for (int ni = 0; ni < 2; ni++)
            for (int i = 0; i < 4; i++) {
                int m = m0 + wm + mi * 16 + quad * 4 + i;
                int n = n0 + wn + ni * 16 + lr;
                Out[(long)m * EMBED + n] = acc[mi][ni][i] + bias[n];
            }
}

// ---------------- flash attention: q-split waves, KVBLK=64, K+V dbuf, 32KB LDS ------
// BYTE-IDENTICAL to the r8-proven version (46.3 us). The inner compute chain is
// FROZEN: r5/r6 (unroll), r10 (K-from-global) — semantically-sound transforms of the
// data path feeding the MFMA+cvtpk chain miscompile on this toolchain. Sync-scheme
// changes (r9) pass but don't help: flash is not staging-bound (r8 == r9 counters).
__global__ __launch_bounds__(256, 4) void flash_attn(const short* __restrict__ Q,
        const short* __restrict__ K, const short* __restrict__ Vt,
        short* __restrict__ Out) {
    extern __shared__ char pool[];
    short* Ks = (short*)pool;             // [2][64*64] shorts = 16 KB
    short* Vs = Ks + 2 * 64 * 64;         // [2][64*64] shorts = 16 KB

    const int bh = blockIdx.y;
    const int tid = threadIdx.x, lane = tid & 63, wid = tid >> 6;
    const int quad = lane >> 4, lr = lane & 15;
    const int q0 = blockIdx.x * 64;
    const int qw = q0 + wid * 16;         // wave's q base (exclusive ownership)

    const short* Qb = Q  + (long)bh * SEQ * HDIM;
    const short* Kb = K  + (long)bh * SEQ * HDIM;
    const short* Vb = Vt + (long)bh * HDIM * SEQ;

    // Q fragments (B-operand: lane lr = q row, k = d = hh*32 + quad*8 + j)
    s8v qf[2];
#pragma unroll
    for (int hh = 0; hh < 2; hh++)
        qf[hh] = *(const s8v*)&Qb[(qw + lr) * HDIM + hh * 32 + quad * 8];

    f4v o[4];
#pragma unroll
    for (int dt = 0; dt < 4; dt++)
        for (int i = 0; i < 4; i++) o[dt][i] = 0.f;
    float lsum = 0.f;

    // p = exp(s/8 - 16) = exp2(s_scaled + SB2); scale folded into Q upstream
    const float SB2 = -16.0f * 1.44269504f;

    const int srow  = lane >> 3;                 // row within 8-row staging group
    const int sslot = (lane & 7) ^ srow;         // source chunk for XOR swizzle

    // prologue: K/V tile 0 -> buffers 0 (each wave stages 2 K-rows-groups + 2 V)
#pragma unroll
    for (int i = 0; i < 2; i++) {
        const int r0 = wid * 16 + i * 8;
        gll16(&Kb[(long)(r0 + srow) * HDIM + sslot * 8], &Ks[r0 * 64]);
        gll16(&Vb[(long)(r0 + srow) * SEQ + sslot * 8], &Vs[r0 * 64]);
    }
    __syncthreads();

    for (int r = 0; r < 32; r++) {
        const int cur = r & 1;
        const short* Kc = Ks + cur * (64 * 64);
        const short* Vc = Vs + cur * (64 * 64);
        short* Kn = Ks + (cur ^ 1) * (64 * 64);
        short* Vn = Vs + (cur ^ 1) * (64 * 64);

        // ---- prefetch tile r+1 into the other buffers (4 loads/wave) ----
        if (r < 31) {
            const int kn0 = (r + 1) * 64;
#pragma unroll
            for (int i = 0; i < 2; i++) {
                const int r0 = wid * 16 + i * 8;
                gll16(&Kb[(long)(kn0 + r0 + srow) * HDIM + sslot * 8], &Kn[r0 * 64]);
                gll16(&Vb[(long)(r0 + srow) * SEQ + kn0 + sslot * 8], &Vn[r0 * 64]);
            }
        }

        // ---- QK^T + softmax: 16 q rows x 64 keys ----
        // lane (quad,lr) gets p[q=qw+lr][key = nt*16 + quad*4 + i]
        unsigned pw[2][4];    // [k-half h][4 dwords] -> A-fragment, slot (quad,j):
                              // key = h*32 + (j>>2)*16 + quad*4 + (j&3)
#pragma unroll
        for (int nt = 0; nt < 4; nt++) {
            const int row = nt * 16 + lr;
            s8v kf0 = *(const s8v*)&Kc[row * 64 + ((quad ^ (lr & 7)) * 8)];
            s8v kf1 = *(const s8v*)&Kc[row * 64 + (((4 + quad) ^ (lr & 7)) * 8)];
            f4v s = {SB2, SB2, SB2, SB2};
            s = __builtin_amdgcn_mfma_f32_16x16x32_bf16(kf0, qf[0], s, 0, 0, 0);
            s = __builtin_amdgcn_mfma_f32_16x16x32_bf16(kf1, qf[1], s, 0, 0, 0);
            float p0 = fexp2(s[0]);
            float p1 = fexp2(s[1]);
            float p2 = fexp2(s[2]);
            float p3 = fexp2(s[3]);
            lsum += (p0 + p1) + (p2 + p3);
            pw[nt >> 1][(nt & 1) * 2]     = cvtpk(p0, p1);
            pw[nt >> 1][(nt & 1) * 2 + 1] = cvtpk(p2, p3);
        }

        // ---- PV: o[16 q][64 d] += P[16 q][64 k] * V[64 k][64 d] ----
#pragma unroll
        for (int h = 0; h < 2; h++) {
            s8v pf = *(s8v*)&pw[h][0];
            const int cb0 = h * 4 + (quad >> 1);      // chunk of keys h*32+quad*4..
#pragma unroll
            for (int dt = 0; dt < 4; dt++) {
                const int d = dt * 16 + lr;
                const int c0 = cb0 ^ (lr & 7);
                const int c1 = (cb0 + 2) ^ (lr & 7);
                s4v v0 = *(const s4v*)&Vc[d * 64 + c0 * 8 + (quad & 1) * 4];
                s4v v1 = *(const s4v*)&Vc[d * 64 + c1 * 8 + (quad & 1) * 4];
                s8v vf = __builtin_shufflevector(v0, v1, 0, 1, 2, 3, 4, 5, 6, 7);
                o[dt] = __builtin_amdgcn_mfma_f32_16x16x32_bf16(pf, vf, o[dt], 0, 0, 0);
            }
        }
        __syncthreads();   // drains prefetch (vmcnt0) + all LDS reads (lgkmcnt0)
    }

    // ---- epilogue: reduce lsum across quads, redistribute, scale, store ----
    lsum += __shfl_xor(lsum, 16);
    lsum += __shfl_xor(lsum, 32);      // lane L now holds full sum for q-row (L&15)
    float linv[4];
#pragma unroll
    for (int i = 0; i < 4; i++)
        linv[i] = 1.0f / __shfl(lsum, quad * 4 + i);

    const int b = bh / HEADS, h = bh % HEADS;
#pragma unroll
    for (int dt = 0; dt < 4; dt++)
#pragma unroll
        for (int i = 0; i < 4; i++) {
            const int q = qw + quad * 4 + i;
            Out[((long)(b * SEQ + q)) * EMBED + h * HDIM + dt * 16 + lr] =
                f2bf(o[dt][i] * linv[i]);
        }
}

extern "C" void kernel_launch(void* const* d_in, const int* in_sizes, int n_in,
                              void* d_out, int out_size, void* d_ws, size_t ws_size,
                              hipStream_t stream) {
    const float* x   = (const float*)d_in[0];
    const float* w_q = (const float*)d_in[1];
    const float* b_q = (const float*)d_in[2];
    const float* w_k = (const float*)d_in[3];
    const float* b_k = (const float*)d_in[4];
    const float* w_v = (const float*)d_in[5];
    const float* b_v = (const float*)d_in[6];
    const float* w_o = (const float*)d_in[7];
    const float* b_o = (const float*)d_in[8];

    short* x_bf   = (short*)d_ws;
    short* wq_bf  = x_bf  + MTOT * EMBED;
    short* wk_bf  = wq_bf + EMBED * EMBED;
    short* wv_bf  = wk_bf + EMBED * EMBED;
    short* wo_bf  = wv_bf + EMBED * EMBED;
    short* q_bf   = wo_bf + EMBED * EMBED;              // [b,h,s,d] (pre-scaled)
    short* k_bf   = q_bf  + BATCH * HEADS * SEQ * HDIM; // [b,h,s,d]
    short* v_bf   = k_bf  + BATCH * HEADS * SEQ * HDIM; // [b,h,d,s]
    short* att_bf = v_bf  + BATCH * HEADS * SEQ * HDIM; // [b,s,E]

    cvt_all<<<dim3(1024, 5), 256, 0, stream>>>(x, w_q, w_k, w_v, w_o,
                                               x_bf, wq_bf, wk_bf, wv_bf, wo_bf);

    gemm_qkv<<<dim3(MTOT / 128, EMBED / 128, 3), 256, 0, stream>>>(
        x_bf, wq_bf, wk_bf, wv_bf, b_q, b_k, b_v, q_bf, k_bf, v_bf);

    flash_attn<<<dim3(SEQ / 64, BATCH * HEADS), 256, 32768, stream>>>(
        q_bf, k_bf, v_bf, att_bf);

    gemm_out<<<dim3(MTOT / 128, EMBED / 64), 256, 0, stream>>>(
        att_bf, wo_bf, b_o, (float*)d_out);
}

// Round 12
// 161.970 us; speedup vs baseline: 1.0000x; 1.0000x over previous
//
#include <hip/hip_runtime.h>
#include <math.h>

#define EMBED 768
#define HEADS 12
#define HDIM 64
#define BATCH 2
#define SEQ 2048
#define MTOT (BATCH*SEQ)   // 4096

typedef short s8v __attribute__((ext_vector_type(8)));
typedef short s4v __attribute__((ext_vector_type(4)));
typedef float f4v __attribute__((ext_vector_type(4)));

__device__ __forceinline__ short f2bf(float f) {
    union { float f; unsigned u; } v; v.f = f;
    unsigned r = v.u + 0x7FFFu + ((v.u >> 16) & 1u);
    return (short)(r >> 16);
}

// pack two floats -> two bf16 in one dword (manual; used in GEMM epilogue)
__device__ __forceinline__ unsigned pk2bf(float a, float b) {
    union { float f; unsigned u; } x, y; x.f = a; y.f = b;
    return ((y.u + 0x8000u) & 0xFFFF0000u) | ((x.u + 0x8000u) >> 16);
}

// HW packed convert: D.lo = bf16(a), D.hi = bf16(b), RNE
__device__ __forceinline__ unsigned cvtpk(float a, float b) {
    unsigned r;
    asm("v_cvt_pk_bf16_f32 %0, %1, %2" : "=v"(r) : "v"(a), "v"(b));
    return r;
}

__device__ __forceinline__ float fexp2(float x) {
#if __has_builtin(__builtin_amdgcn_exp2f)
    return __builtin_amdgcn_exp2f(x);
#else
    return exp2f(x);
#endif
}

// async global->LDS, 16B/lane; lds base wave-uniform, lane scatter on GLOBAL side ok
__device__ __forceinline__ void gll16(const short* g, short* l) {
    __builtin_amdgcn_global_load_lds((const __attribute__((address_space(1))) void*)g,
                                     (__attribute__((address_space(3))) void*)l, 16, 0, 0);
}

// ---------------- fp32 -> bf16 converts ----------------
__global__ __launch_bounds__(256) void cvt_all(
        const float* __restrict__ x,  const float* __restrict__ wq,
        const float* __restrict__ wk, const float* __restrict__ wv,
        const float* __restrict__ wo,
        short* __restrict__ xb, short* __restrict__ wqb, short* __restrict__ wkb,
        short* __restrict__ wvb, short* __restrict__ wob) {
    const int seg = blockIdx.y;
    const float* src; short* dst; int n4;
    if      (seg == 0) { src = x;  dst = xb;  n4 = MTOT * EMBED / 4; }
    else if (seg == 1) { src = wq; dst = wqb; n4 = EMBED * EMBED / 4; }
    else if (seg == 2) { src = wk; dst = wkb; n4 = EMBED * EMBED / 4; }
    else if (seg == 3) { src = wv; dst = wvb; n4 = EMBED * EMBED / 4; }
    else               { src = wo; dst = wob; n4 = EMBED * EMBED / 4; }
    for (int i = blockIdx.x * 256 + threadIdx.x; i < n4; i += gridDim.x * 256) {
        float4 f = ((const float4*)src)[i];
        short4 o;
        o.x = f2bf(f.x); o.y = f2bf(f.y); o.z = f2bf(f.z); o.w = f2bf(f.w);
        ((short4*)dst)[i] = o;
    }
}

// ---------------- fused QKV GEMM (BM=64, BN=128, BK=64, XOR-swizzled LDS) -----------
// C[m][n] = sum_k A[m][k]*W[n][k] + bias[n]
// mode(z): 0->Q [b,h,s,d] pre-scaled by 0.125*log2(e), 1->K [b,h,s,d], 2->V [b,h,d,s]
// r8-proven BK=64 structure (12 drains, -9us vs BK=32); BM halved 128->64 to double
// the grid (64x6x3 = 1728 blocks = 4.5/CU vs 2.25) — with the 2-phase full-drain
// scheme, drains are hidden only by co-resident blocks, and r8/r11 showed the GEMMs
// are drain-bound with too little TLP. W restage doubles but W (1.2MB) is L2-resident.
// Swizzle: chunk c of row r at slot c^(r&7); fragment reads XOR lr&7 (row&7==lr&7).
__global__ __launch_bounds__(256, 4) void gemm_qkv(const short* __restrict__ A,
        const short* __restrict__ Wq, const short* __restrict__ Wk, const short* __restrict__ Wv,
        const float* __restrict__ bq, const float* __restrict__ bk, const float* __restrict__ bv,
        short* __restrict__ Qo, short* __restrict__ Ko, short* __restrict__ Vo) {
    const int mode = blockIdx.z;
    const short* W    = (mode == 0) ? Wq : (mode == 1) ? Wk : Wv;
    const float* bias = (mode == 0) ? bq : (mode == 1) ? bk : bv;
    // fold softmax scale (1/8) and log2(e) into Q so flash needs no fmaf on scores
    const float qs = (mode == 0) ? (0.125f * 1.44269504f) : 1.0f;

    __shared__ short As[64 * 64];    // 8 KB, rows of 128 B, XOR-swizzled
    __shared__ short Ws[128 * 64];   // 16 KB

    const int tid = threadIdx.x;
    const int lane = tid & 63, wid = tid >> 6;
    const int quad = lane >> 4, lr = lane & 15;
    const int m0 = blockIdx.x * 64, n0 = blockIdx.y * 128;
    const int wm = (wid >> 1) * 32, wn = (wid & 1) * 64;

    const int srow  = lane >> 3;                 // row within 8-row staging group
    const int sslot = (lane & 7) ^ srow;         // source chunk for XOR swizzle

    f4v acc[2][4];
    for (int a = 0; a < 2; a++)
        for (int b = 0; b < 4; b++)
            for (int i = 0; i < 4; i++) acc[a][b][i] = 0.f;

    for (int k0 = 0; k0 < EMBED; k0 += 64) {
        // stage A[64][64] (wave: rows wid*16..+16) + W[128][64] (wave: rows wid*32..+32)
#pragma unroll
        for (int i = 0; i < 2; i++) {
            const int r0 = wid * 16 + i * 8;
            gll16(&A[(long)(m0 + r0 + srow) * EMBED + k0 + sslot * 8], &As[r0 * 64]);
        }
#pragma unroll
        for (int i = 0; i < 4; i++) {
            const int r0 = wid * 32 + i * 8;
            gll16(&W[(long)(n0 + r0 + srow) * EMBED + k0 + sslot * 8], &Ws[r0 * 64]);
        }
        __syncthreads();

#pragma unroll
        for (int kk = 0; kk < 2; kk++) {
            s8v af[2], bf[4];
            for (int mi = 0; mi < 2; mi++)
                af[mi] = *(const s8v*)&As[(wm + mi * 16 + lr) * 64 + (((kk * 4 + quad) ^ (lr & 7)) * 8)];
            for (int ni = 0; ni < 4; ni++)
                bf[ni] = *(const s8v*)&Ws[(wn + ni * 16 + lr) * 64 + (((kk * 4 + quad) ^ (lr & 7)) * 8)];
            for (int mi = 0; mi < 2; mi++)
                for (int ni = 0; ni < 4; ni++)
                    acc[mi][ni] = __builtin_amdgcn_mfma_f32_16x16x32_bf16(af[mi], bf[ni], acc[mi][ni], 0, 0, 0);
        }
        __syncthreads();
    }

    if (mode == 2) {
        for (int mi = 0; mi < 2; mi++) {
            int srow2 = m0 + wm + mi * 16 + quad * 4;
            int b = srow2 >> 11, s = srow2 & 2047;
            for (int ni = 0; ni < 4; ni++) {
                int n = n0 + wn + ni * 16 + lr;
                int h = n >> 6, d = n & 63;
                float bb = bias[n];
                uint2 pk;
                pk.x = pk2bf(acc[mi][ni][0] + bb, acc[mi][ni][1] + bb);
                pk.y = pk2bf(acc[mi][ni][2] + bb, acc[mi][ni][3] + bb);
                *(uint2*)&Vo[(((long)(b * HEADS + h) * HDIM + d) * SEQ) + s] = pk;
            }
        }
    } else {
        short* Out = (mode == 0) ? Qo : Ko;
        for (int mi = 0; mi < 2; mi++) {
            for (int ni = 0; ni < 4; ni++) {
                int n = n0 + wn + ni * 16 + lr;
                int h = n >> 6, d = n & 63;
                float bb = bias[n];
                for (int i = 0; i < 4; i++) {
                    int m = m0 + wm + mi * 16 + quad * 4 + i;
                    int b = m >> 11, s = m & 2047;
                    Out[(((long)(b * HEADS + h) * SEQ + s) * HDIM) + d] =
                        f2bf((acc[mi][ni][i] + bb) * qs);
                }
            }
        }
    }
}

// ---------------- output projection GEMM (BM=64, BN=64, BK=64, XOR-swizzled) --------
// Grid 64x12 = 768 blocks = 3/CU (was 1.5/CU at BM=128) — same TLP rationale.
__global__ __launch_bounds__(256, 4) void gemm_out(const short* __restrict__ A,
        const short* __restrict__ W, const float* __restrict__ bias,
        float* __restrict__ Out) {
    __shared__ short As[64 * 64];    // 8 KB
    __shared__ short Ws[64 * 64];    // 8 KB

    const int tid = threadIdx.x;
    const int lane = tid & 63, wid = tid >> 6;
    const int quad = lane >> 4, lr = lane & 15;
    const int m0 = blockIdx.x * 64, n0 = blockIdx.y * 64;
    const int wm = (wid >> 1) * 32, wn = (wid & 1) * 32;

    const int srow  = lane >> 3;
    const int sslot = (lane & 7) ^ srow;

    f4v acc[2][2];
    for (int a = 0; a < 2; a++)
        for (int b = 0; b < 2; b++)
            for (int i = 0; i < 4; i++) acc[a][b][i] = 0.f;

    for (int k0 = 0; k0 < EMBED; k0 += 64) {
#pragma unroll
        for (int i = 0; i < 2; i++) {
            const int r0 = wid * 16 + i * 8;
            gll16(&A[(long)(m0 + r0 + srow) * EMBED + k0 + sslot * 8], &As[r0 * 64]);
            gll16(&W[(long)(n0 + r0 + srow) * EMBED + k0 + sslot * 8], &Ws[r0 * 64]);
        }
        __syncthreads();

#pragma unroll
        for (int kk = 0; kk < 2; kk++) {
            s8v af[2], bf[2];
            for (int mi = 0; mi < 2; mi++)
                af[mi] = *(const s8v*)&As[(wm + mi * 16 + lr) * 64 + (((kk * 4 + quad) ^ (lr & 7)) * 8)];
            for (int ni = 0; ni < 2; ni++)
                bf[ni] = *(const s8v*)&Ws[(wn + ni * 16 + lr) * 64 + (((kk * 4 + quad) ^ (lr & 7)) * 8)];
            for (int mi = 0; mi < 2; mi++)
                for (int ni = 0; ni < 2; ni++)
                    acc[mi][ni] = __builtin_amdgcn_mfma_f32_16x16x32_bf16(af[mi], bf[ni], acc[mi][ni], 0, 0, 0);
        }
        __syncthreads();
    }

    for (int mi = 0; mi < 2; mi++)
        for (int ni = 0; ni < 2; ni++)
            for (int i = 0; i < 4; i++) {
                int m = m0 + wm + mi * 16 + quad * 4 + i;
                int n = n0 + wn + ni * 16 + lr;
                Out[(long)m * EMBED + n] = acc[mi][ni][i] + bias[n];
            }
}

// ---------------- flash attention: q-split waves, KVBLK=64, K+V dbuf, 32KB LDS ------
// BYTE-IDENTICAL to the r8-proven version (46.3 us). The inner compute chain is
// FROZEN: r5/r6 (unroll), r10 (K-from-global) — semantically-sound transforms of the
// data path feeding the MFMA+cvtpk chain miscompile on this toolchain. Sync-scheme
// changes (r9) pass but don't help: flash is not staging-bound (r8 == r9 counters).
__global__ __launch_bounds__(256, 4) void flash_attn(const short* __restrict__ Q,
        const short* __restrict__ K, const short* __restrict__ Vt,
        short* __restrict__ Out) {
    extern __shared__ char pool[];
    short* Ks = (short*)pool;             // [2][64*64] shorts = 16 KB
    short* Vs = Ks + 2 * 64 * 64;         // [2][64*64] shorts = 16 KB

    const int bh = blockIdx.y;
    const int tid = threadIdx.x, lane = tid & 63, wid = tid >> 6;
    const int quad = lane >> 4, lr = lane & 15;
    const int q0 = blockIdx.x * 64;
    const int qw = q0 + wid * 16;         // wave's q base (exclusive ownership)

    const short* Qb = Q  + (long)bh * SEQ * HDIM;
    const short* Kb = K  + (long)bh * SEQ * HDIM;
    const short* Vb = Vt + (long)bh * HDIM * SEQ;

    // Q fragments (B-operand: lane lr = q row, k = d = hh*32 + quad*8 + j)
    s8v qf[2];
#pragma unroll
    for (int hh = 0; hh < 2; hh++)
        qf[hh] = *(const s8v*)&Qb[(qw + lr) * HDIM + hh * 32 + quad * 8];

    f4v o[4];
#pragma unroll
    for (int dt = 0; dt < 4; dt++)
        for (int i = 0; i < 4; i++) o[dt][i] = 0.f;
    float lsum = 0.f;

    // p = exp(s/8 - 16) = exp2(s_scaled + SB2); scale folded into Q upstream
    const float SB2 = -16.0f * 1.44269504f;

    const int srow  = lane >> 3;                 // row within 8-row staging group
    const int sslot = (lane & 7) ^ srow;         // source chunk for XOR swizzle

    // prologue: K/V tile 0 -> buffers 0 (each wave stages 2 K-rows-groups + 2 V)
#pragma unroll
    for (int i = 0; i < 2; i++) {
        const int r0 = wid * 16 + i * 8;
        gll16(&Kb[(long)(r0 + srow) * HDIM + sslot * 8], &Ks[r0 * 64]);
        gll16(&Vb[(long)(r0 + srow) * SEQ + sslot * 8], &Vs[r0 * 64]);
    }
    __syncthreads();

    for (int r = 0; r < 32; r++) {
        const int cur = r & 1;
        const short* Kc = Ks + cur * (64 * 64);
        const short* Vc = Vs + cur * (64 * 64);
        short* Kn = Ks + (cur ^ 1) * (64 * 64);
        short* Vn = Vs + (cur ^ 1) * (64 * 64);

        // ---- prefetch tile r+1 into the other buffers (4 loads/wave) ----
        if (r < 31) {
            const int kn0 = (r + 1) * 64;
#pragma unroll
            for (int i = 0; i < 2; i++) {
                const int r0 = wid * 16 + i * 8;
                gll16(&Kb[(long)(kn0 + r0 + srow) * HDIM + sslot * 8], &Kn[r0 * 64]);
                gll16(&Vb[(long)(r0 + srow) * SEQ + kn0 + sslot * 8], &Vn[r0 * 64]);
            }
        }

        // ---- QK^T + softmax: 16 q rows x 64 keys ----
        // lane (quad,lr) gets p[q=qw+lr][key = nt*16 + quad*4 + i]
        unsigned pw[2][4];    // [k-half h][4 dwords] -> A-fragment, slot (quad,j):
                              // key = h*32 + (j>>2)*16 + quad*4 + (j&3)
#pragma unroll
        for (int nt = 0; nt < 4; nt++) {
            const int row = nt * 16 + lr;
            s8v kf0 = *(const s8v*)&Kc[row * 64 + ((quad ^ (lr & 7)) * 8)];
            s8v kf1 = *(const s8v*)&Kc[row * 64 + (((4 + quad) ^ (lr & 7)) * 8)];
            f4v s = {SB2, SB2, SB2, SB2};
            s = __builtin_amdgcn_mfma_f32_16x16x32_bf16(kf0, qf[0], s, 0, 0, 0);
            s = __builtin_amdgcn_mfma_f32_16x16x32_bf16(kf1, qf[1], s, 0, 0, 0);
            float p0 = fexp2(s[0]);
            float p1 = fexp2(s[1]);
            float p2 = fexp2(s[2]);
            float p3 = fexp2(s[3]);
            lsum += (p0 + p1) + (p2 + p3);
            pw[nt >> 1][(nt & 1) * 2]     = cvtpk(p0, p1);
            pw[nt >> 1][(nt & 1) * 2 + 1] = cvtpk(p2, p3);
        }

        // ---- PV: o[16 q][64 d] += P[16 q][64 k] * V[64 k][64 d] ----
#pragma unroll
        for (int h = 0; h < 2; h++) {
            s8v pf = *(s8v*)&pw[h][0];
            const int cb0 = h * 4 + (quad >> 1);      // chunk of keys h*32+quad*4..
#pragma unroll
            for (int dt = 0; dt < 4; dt++) {
                const int d = dt * 16 + lr;
                const int c0 = cb0 ^ (lr & 7);
                const int c1 = (cb0 + 2) ^ (lr & 7);
                s4v v0 = *(const s4v*)&Vc[d * 64 + c0 * 8 + (quad & 1) * 4];
                s4v v1 = *(const s4v*)&Vc[d * 64 + c1 * 8 + (quad & 1) * 4];
                s8v vf = __builtin_shufflevector(v0, v1, 0, 1, 2, 3, 4, 5, 6, 7);
                o[dt] = __builtin_amdgcn_mfma_f32_16x16x32_bf16(pf, vf, o[dt], 0, 0, 0);
            }
        }
        __syncthreads();   // drains prefetch (vmcnt0) + all LDS reads (lgkmcnt0)
    }

    // ---- epilogue: reduce lsum across quads, redistribute, scale, store ----
    lsum += __shfl_xor(lsum, 16);
    lsum += __shfl_xor(lsum, 32);      // lane L now holds full sum for q-row (L&15)
    float linv[4];
#pragma unroll
    for (int i = 0; i < 4; i++)
        linv[i] = 1.0f / __shfl(lsum, quad * 4 + i);

    const int b = bh / HEADS, h = bh % HEADS;
#pragma unroll
    for (int dt = 0; dt < 4; dt++)
#pragma unroll
        for (int i = 0; i < 4; i++) {
            const int q = qw + quad * 4 + i;
            Out[((long)(b * SEQ + q)) * EMBED + h * HDIM + dt * 16 + lr] =
                f2bf(o[dt][i] * linv[i]);
        }
}

extern "C" void kernel_launch(void* const* d_in, const int* in_sizes, int n_in,
                              void* d_out, int out_size, void* d_ws, size_t ws_size,
                              hipStream_t stream) {
    const float* x   = (const float*)d_in[0];
    const float* w_q = (const float*)d_in[1];
    const float* b_q = (const float*)d_in[2];
    const float* w_k = (const float*)d_in[3];
    const float* b_k = (const float*)d_in[4];
    const float* w_v = (const float*)d_in[5];
    const float* b_v = (const float*)d_in[6];
    const float* w_o = (const float*)d_in[7];
    const float* b_o = (const float*)d_in[8];

    short* x_bf   = (short*)d_ws;
    short* wq_bf  = x_bf  + MTOT * EMBED;
    short* wk_bf  = wq_bf + EMBED * EMBED;
    short* wv_bf  = wk_bf + EMBED * EMBED;
    short* wo_bf  = wv_bf + EMBED * EMBED;
    short* q_bf   = wo_bf + EMBED * EMBED;              // [b,h,s,d] (pre-scaled)
    short* k_bf   = q_bf  + BATCH * HEADS * SEQ * HDIM; // [b,h,s,d]
    short* v_bf   = k_bf  + BATCH * HEADS * SEQ * HDIM; // [b,h,d,s]
    short* att_bf = v_bf  + BATCH * HEADS * SEQ * HDIM; // [b,s,E]

    cvt_all<<<dim3(1024, 5), 256, 0, stream>>>(x, w_q, w_k, w_v, w_o,
                                               x_bf, wq_bf, wk_bf, wv_bf, wo_bf);

    gemm_qkv<<<dim3(MTOT / 64, EMBED / 128, 3), 256, 0, stream>>>(
        x_bf, wq_bf, wk_bf, wv_bf, b_q, b_k, b_v, q_bf, k_bf, v_bf);

    flash_attn<<<dim3(SEQ / 64, BATCH * HEADS), 256, 32768, stream>>>(
        q_bf, k_bf, v_bf, att_bf);

    gemm_out<<<dim3(MTOT / 64, EMBED / 64), 256, 0, stream>>>(
        att_bf, wo_bf, b_o, (float*)d_out);
}

// Round 13
// 152.900 us; speedup vs baseline: 1.0593x; 1.0593x over previous
//
#include <hip/hip_runtime.h>
#include <math.h>

#define EMBED 768
#define HEADS 12
#define HDIM 64
#define BATCH 2
#define SEQ 2048
#define MTOT (BATCH*SEQ)   // 4096

typedef short s8v __attribute__((ext_vector_type(8)));
typedef short s4v __attribute__((ext_vector_type(4)));
typedef float f4v __attribute__((ext_vector_type(4)));

__device__ __forceinline__ short f2bf(float f) {
    union { float f; unsigned u; } v; v.f = f;
    unsigned r = v.u + 0x7FFFu + ((v.u >> 16) & 1u);
    return (short)(r >> 16);
}

// pack two floats -> two bf16 in one dword (manual; used in GEMM epilogue)
__device__ __forceinline__ unsigned pk2bf(float a, float b) {
    union { float f; unsigned u; } x, y; x.f = a; y.f = b;
    return ((y.u + 0x8000u) & 0xFFFF0000u) | ((x.u + 0x8000u) >> 16);
}

// HW packed convert: D.lo = bf16(a), D.hi = bf16(b), RNE
__device__ __forceinline__ unsigned cvtpk(float a, float b) {
    unsigned r;
    asm("v_cvt_pk_bf16_f32 %0, %1, %2" : "=v"(r) : "v"(a), "v"(b));
    return r;
}

__device__ __forceinline__ float fexp2(float x) {
#if __has_builtin(__builtin_amdgcn_exp2f)
    return __builtin_amdgcn_exp2f(x);
#else
    return exp2f(x);
#endif
}

// async global->LDS, 16B/lane; lds base wave-uniform, lane scatter on GLOBAL side ok
__device__ __forceinline__ void gll16(const short* g, short* l) {
    __builtin_amdgcn_global_load_lds((const __attribute__((address_space(1))) void*)g,
                                     (__attribute__((address_space(3))) void*)l, 16, 0, 0);
}

// ---------------- fp32 -> bf16 converts ----------------
__global__ __launch_bounds__(256) void cvt_all(
        const float* __restrict__ x,  const float* __restrict__ wq,
        const float* __restrict__ wk, const float* __restrict__ wv,
        const float* __restrict__ wo,
        short* __restrict__ xb, short* __restrict__ wqb, short* __restrict__ wkb,
        short* __restrict__ wvb, short* __restrict__ wob) {
    const int seg = blockIdx.y;
    const float* src; short* dst; int n4;
    if      (seg == 0) { src = x;  dst = xb;  n4 = MTOT * EMBED / 4; }
    else if (seg == 1) { src = wq; dst = wqb; n4 = EMBED * EMBED / 4; }
    else if (seg == 2) { src = wk; dst = wkb; n4 = EMBED * EMBED / 4; }
    else if (seg == 3) { src = wv; dst = wvb; n4 = EMBED * EMBED / 4; }
    else               { src = wo; dst = wob; n4 = EMBED * EMBED / 4; }
    for (int i = blockIdx.x * 256 + threadIdx.x; i < n4; i += gridDim.x * 256) {
        float4 f = ((const float4*)src)[i];
        short4 o;
        o.x = f2bf(f.x); o.y = f2bf(f.y); o.z = f2bf(f.z); o.w = f2bf(f.w);
        ((short4*)dst)[i] = o;
    }
}

// ---------------- fused QKV GEMM (BM=128, BN=128, BK=64, XOR-swizzled LDS) ----------
// r8-proven best (155.7 us total). C[m][n] = sum_k A[m][k]*W[n][k] + bias[n]
// mode(z): 0->Q [b,h,s,d] pre-scaled by 0.125*log2(e), 1->K [b,h,s,d], 2->V [b,h,d,s]
// BK=64 halves the per-K-step barrier/vmcnt0 drains (12 steps vs 24) — measured -9 us.
// Tile-space around this structure is locally optimal: BK32=+8, counted-vmcnt=+6,
// BM64=+6 (r0/r11/r12 measurements). Swizzle: chunk c of row r at slot c^(r&7);
// fragment reads XOR lr&7 (fragment rows satisfy row&7 == lr&7).
__global__ __launch_bounds__(256, 4) void gemm_qkv(const short* __restrict__ A,
        const short* __restrict__ Wq, const short* __restrict__ Wk, const short* __restrict__ Wv,
        const float* __restrict__ bq, const float* __restrict__ bk, const float* __restrict__ bv,
        short* __restrict__ Qo, short* __restrict__ Ko, short* __restrict__ Vo) {
    const int mode = blockIdx.z;
    const short* W    = (mode == 0) ? Wq : (mode == 1) ? Wk : Wv;
    const float* bias = (mode == 0) ? bq : (mode == 1) ? bk : bv;
    // fold softmax scale (1/8) and log2(e) into Q so flash needs no fmaf on scores
    const float qs = (mode == 0) ? (0.125f * 1.44269504f) : 1.0f;

    __shared__ short As[128 * 64];   // 16 KB, rows of 128 B, XOR-swizzled
    __shared__ short Ws[128 * 64];   // 16 KB

    const int tid = threadIdx.x;
    const int lane = tid & 63, wid = tid >> 6;
    const int quad = lane >> 4, lr = lane & 15;
    const int m0 = blockIdx.x * 128, n0 = blockIdx.y * 128;
    const int wm = (wid >> 1) * 64, wn = (wid & 1) * 64;

    const int srow  = lane >> 3;                 // row within 8-row staging group
    const int sslot = (lane & 7) ^ srow;         // source chunk for XOR swizzle

    f4v acc[4][4];
    for (int a = 0; a < 4; a++)
        for (int b = 0; b < 4; b++)
            for (int i = 0; i < 4; i++) acc[a][b][i] = 0.f;

    for (int k0 = 0; k0 < EMBED; k0 += 64) {
        // stage A[128][64] + W[128][64]; wave stages rows [wid*32, wid*32+32) of each
#pragma unroll
        for (int i = 0; i < 4; i++) {
            const int r0 = wid * 32 + i * 8;
            gll16(&A[(long)(m0 + r0 + srow) * EMBED + k0 + sslot * 8], &As[r0 * 64]);
            gll16(&W[(long)(n0 + r0 + srow) * EMBED + k0 + sslot * 8], &Ws[r0 * 64]);
        }
        __syncthreads();

#pragma unroll
        for (int kk = 0; kk < 2; kk++) {
            s8v af[4], bf[4];
            for (int mi = 0; mi < 4; mi++)
                af[mi] = *(const s8v*)&As[(wm + mi * 16 + lr) * 64 + (((kk * 4 + quad) ^ (lr & 7)) * 8)];
            for (int ni = 0; ni < 4; ni++)
                bf[ni] = *(const s8v*)&Ws[(wn + ni * 16 + lr) * 64 + (((kk * 4 + quad) ^ (lr & 7)) * 8)];
            for (int mi = 0; mi < 4; mi++)
                for (int ni = 0; ni < 4; ni++)
                    acc[mi][ni] = __builtin_amdgcn_mfma_f32_16x16x32_bf16(af[mi], bf[ni], acc[mi][ni], 0, 0, 0);
        }
        __syncthreads();
    }

    if (mode == 2) {
        for (int mi = 0; mi < 4; mi++) {
            int srow2 = m0 + wm + mi * 16 + quad * 4;
            int b = srow2 >> 11, s = srow2 & 2047;
            for (int ni = 0; ni < 4; ni++) {
                int n = n0 + wn + ni * 16 + lr;
                int h = n >> 6, d = n & 63;
                float bb = bias[n];
                uint2 pk;
                pk.x = pk2bf(acc[mi][ni][0] + bb, acc[mi][ni][1] + bb);
                pk.y = pk2bf(acc[mi][ni][2] + bb, acc[mi][ni][3] + bb);
                *(uint2*)&Vo[(((long)(b * HEADS + h) * HDIM + d) * SEQ) + s] = pk;
            }
        }
    } else {
        short* Out = (mode == 0) ? Qo : Ko;
        for (int mi = 0; mi < 4; mi++) {
            for (int ni = 0; ni < 4; ni++) {
                int n = n0 + wn + ni * 16 + lr;
                int h = n >> 6, d = n & 63;
                float bb = bias[n];
                for (int i = 0; i < 4; i++) {
                    int m = m0 + wm + mi * 16 + quad * 4 + i;
                    int b = m >> 11, s = m & 2047;
                    Out[(((long)(b * HEADS + h) * SEQ + s) * HDIM) + d] =
                        f2bf((acc[mi][ni][i] + bb) * qs);
                }
            }
        }
    }
}

// ---------------- output projection GEMM (BM=64, BN=64, BK=64, XOR-swizzled) --------
// r12-proven code. Grid 64x12 = 768 blocks = exactly 3/CU (the r8 BM=128/BN=64 form
// was 384 blocks = 1.5/CU: half the CUs idle for the whole second scheduling round).
// This is the only piece of r12 with a load-balance argument independent of the
// drain-count model; unbundled here as a single-variable A/B vs r8.
__global__ __launch_bounds__(256, 4) void gemm_out(const short* __restrict__ A,
        const short* __restrict__ W, const float* __restrict__ bias,
        float* __restrict__ Out) {
    __shared__ short As[64 * 64];    // 8 KB
    __shared__ short Ws[64 * 64];    // 8 KB

    const int tid = threadIdx.x;
    const int lane = tid & 63, wid = tid >> 6;
    const int quad = lane >> 4, lr = lane & 15;
    const int m0 = blockIdx.x * 64, n0 = blockIdx.y * 64;
    const int wm = (wid >> 1) * 32, wn = (wid & 1) * 32;

    const int srow  = lane >> 3;
    const int sslot = (lane & 7) ^ srow;

    f4v acc[2][2];
    for (int a = 0; a < 2; a++)
        for (int b = 0; b < 2; b++)
            for (int i = 0; i < 4; i++) acc[a][b][i] = 0.f;

    for (int k0 = 0; k0 < EMBED; k0 += 64) {
#pragma unroll
        for (int i = 0; i < 2; i++) {
            const int r0 = wid * 16 + i * 8;
            gll16(&A[(long)(m0 + r0 + srow) * EMBED + k0 + sslot * 8], &As[r0 * 64]);
            gll16(&W[(long)(n0 + r0 + srow) * EMBED + k0 + sslot * 8], &Ws[r0 * 64]);
        }
        __syncthreads();

#pragma unroll
        for (int kk = 0; kk < 2; kk++) {
            s8v af[2], bf[2];
            for (int mi = 0; mi < 2; mi++)
                af[mi] = *(const s8v*)&As[(wm + mi * 16 + lr) * 64 + (((kk * 4 + quad) ^ (lr & 7)) * 8)];
            for (int ni = 0; ni < 2; ni++)
                bf[ni] = *(const s8v*)&Ws[(wn + ni * 16 + lr) * 64 + (((kk * 4 + quad) ^ (lr & 7)) * 8)];
            for (int mi = 0; mi < 2; mi++)
                for (int ni = 0; ni < 2; ni++)
                    acc[mi][ni] = __builtin_amdgcn_mfma_f32_16x16x32_bf16(af[mi], bf[ni], acc[mi][ni], 0, 0, 0);
        }
        __syncthreads();
    }

    for (int mi = 0; mi < 2; mi++)
        for (int ni = 0; ni < 2; ni++)
            for (int i = 0; i < 4; i++) {
                int m = m0 + wm + mi * 16 + quad * 4 + i;
                int n = n0 + wn + ni * 16 + lr;
                Out[(long)m * EMBED + n] = acc[mi][ni][i] + bias[n];
            }
}

// ---------------- flash attention: q-split waves, KVBLK=64, K+V dbuf, 32KB LDS ------
// BYTE-IDENTICAL to the r8-proven version (46.3 us). The inner compute chain is
// FROZEN: r5/r6 (unroll), r10 (K-from-global) — semantically-sound transforms of the
// data path feeding the MFMA+cvtpk chain miscompile on this toolchain. Sync-scheme
// changes (r9) pass but don't help: flash is not staging-bound (r8 == r9 counters).
__global__ __launch_bounds__(256, 4) void flash_attn(const short* __restrict__ Q,
        const short* __restrict__ K, const short* __restrict__ Vt,
        short* __restrict__ Out) {
    extern __shared__ char pool[];
    short* Ks = (short*)pool;             // [2][64*64] shorts = 16 KB
    short* Vs = Ks + 2 * 64 * 64;         // [2][64*64] shorts = 16 KB

    const int bh = blockIdx.y;
    const int tid = threadIdx.x, lane = tid & 63, wid = tid >> 6;
    const int quad = lane >> 4, lr = lane & 15;
    const int q0 = blockIdx.x * 64;
    const int qw = q0 + wid * 16;         // wave's q base (exclusive ownership)

    const short* Qb = Q  + (long)bh * SEQ * HDIM;
    const short* Kb = K  + (long)bh * SEQ * HDIM;
    const short* Vb = Vt + (long)bh * HDIM * SEQ;

    // Q fragments (B-operand: lane lr = q row, k = d = hh*32 + quad*8 + j)
    s8v qf[2];
#pragma unroll
    for (int hh = 0; hh < 2; hh++)
        qf[hh] = *(const s8v*)&Qb[(qw + lr) * HDIM + hh * 32 + quad * 8];

    f4v o[4];
#pragma unroll
    for (int dt = 0; dt < 4; dt++)
        for (int i = 0; i < 4; i++) o[dt][i] = 0.f;
    float lsum = 0.f;

    // p = exp(s/8 - 16) = exp2(s_scaled + SB2); scale folded into Q upstream
    const float SB2 = -16.0f * 1.44269504f;

    const int srow  = lane >> 3;                 // row within 8-row staging group
    const int sslot = (lane & 7) ^ srow;         // source chunk for XOR swizzle

    // prologue: K/V tile 0 -> buffers 0 (each wave stages 2 K-rows-groups + 2 V)
#pragma unroll
    for (int i = 0; i < 2; i++) {
        const int r0 = wid * 16 + i * 8;
        gll16(&Kb[(long)(r0 + srow) * HDIM + sslot * 8], &Ks[r0 * 64]);
        gll16(&Vb[(long)(r0 + srow) * SEQ + sslot * 8], &Vs[r0 * 64]);
    }
    __syncthreads();

    for (int r = 0; r < 32; r++) {
        const int cur = r & 1;
        const short* Kc = Ks + cur * (64 * 64);
        const short* Vc = Vs + cur * (64 * 64);
        short* Kn = Ks + (cur ^ 1) * (64 * 64);
        short* Vn = Vs + (cur ^ 1) * (64 * 64);

        // ---- prefetch tile r+1 into the other buffers (4 loads/wave) ----
        if (r < 31) {
            const int kn0 = (r + 1) * 64;
#pragma unroll
            for (int i = 0; i < 2; i++) {
                const int r0 = wid * 16 + i * 8;
                gll16(&Kb[(long)(kn0 + r0 + srow) * HDIM + sslot * 8], &Kn[r0 * 64]);
                gll16(&Vb[(long)(r0 + srow) * SEQ + kn0 + sslot * 8], &Vn[r0 * 64]);
            }
        }

        // ---- QK^T + softmax: 16 q rows x 64 keys ----
        // lane (quad,lr) gets p[q=qw+lr][key = nt*16 + quad*4 + i]
        unsigned pw[2][4];    // [k-half h][4 dwords] -> A-fragment, slot (quad,j):
                              // key = h*32 + (j>>2)*16 + quad*4 + (j&3)
#pragma unroll
        for (int nt = 0; nt < 4; nt++) {
            const int row = nt * 16 + lr;
            s8v kf0 = *(const s8v*)&Kc[row * 64 + ((quad ^ (lr & 7)) * 8)];
            s8v kf1 = *(const s8v*)&Kc[row * 64 + (((4 + quad) ^ (lr & 7)) * 8)];
            f4v s = {SB2, SB2, SB2, SB2};
            s = __builtin_amdgcn_mfma_f32_16x16x32_bf16(kf0, qf[0], s, 0, 0, 0);
            s = __builtin_amdgcn_mfma_f32_16x16x32_bf16(kf1, qf[1], s, 0, 0, 0);
            float p0 = fexp2(s[0]);
            float p1 = fexp2(s[1]);
            float p2 = fexp2(s[2]);
            float p3 = fexp2(s[3]);
            lsum += (p0 + p1) + (p2 + p3);
            pw[nt >> 1][(nt & 1) * 2]     = cvtpk(p0, p1);
            pw[nt >> 1][(nt & 1) * 2 + 1] = cvtpk(p2, p3);
        }

        // ---- PV: o[16 q][64 d] += P[16 q][64 k] * V[64 k][64 d] ----
#pragma unroll
        for (int h = 0; h < 2; h++) {
            s8v pf = *(s8v*)&pw[h][0];
            const int cb0 = h * 4 + (quad >> 1);      // chunk of keys h*32+quad*4..
#pragma unroll
            for (int dt = 0; dt < 4; dt++) {
                const int d = dt * 16 + lr;
                const int c0 = cb0 ^ (lr & 7);
                const int c1 = (cb0 + 2) ^ (lr & 7);
                s4v v0 = *(const s4v*)&Vc[d * 64 + c0 * 8 + (quad & 1) * 4];
                s4v v1 = *(const s4v*)&Vc[d * 64 + c1 * 8 + (quad & 1) * 4];
                s8v vf = __builtin_shufflevector(v0, v1, 0, 1, 2, 3, 4, 5, 6, 7);
                o[dt] = __builtin_amdgcn_mfma_f32_16x16x32_bf16(pf, vf, o[dt], 0, 0, 0);
            }
        }
        __syncthreads();   // drains prefetch (vmcnt0) + all LDS reads (lgkmcnt0)
    }

    // ---- epilogue: reduce lsum across quads, redistribute, scale, store ----
    lsum += __shfl_xor(lsum, 16);
    lsum += __shfl_xor(lsum, 32);      // lane L now holds full sum for q-row (L&15)
    float linv[4];
#pragma unroll
    for (int i = 0; i < 4; i++)
        linv[i] = 1.0f / __shfl(lsum, quad * 4 + i);

    const int b = bh / HEADS, h = bh % HEADS;
#pragma unroll
    for (int dt = 0; dt < 4; dt++)
#pragma unroll
        for (int i = 0; i < 4; i++) {
            const int q = qw + quad * 4 + i;
            Out[((long)(b * SEQ + q)) * EMBED + h * HDIM + dt * 16 + lr] =
                f2bf(o[dt][i] * linv[i]);
        }
}

extern "C" void kernel_launch(void* const* d_in, const int* in_sizes, int n_in,
                              void* d_out, int out_size, void* d_ws, size_t ws_size,
                              hipStream_t stream) {
    const float* x   = (const float*)d_in[0];
    const float* w_q = (const float*)d_in[1];
    const float* b_q = (const float*)d_in[2];
    const float* w_k = (const float*)d_in[3];
    const float* b_k = (const float*)d_in[4];
    const float* w_v = (const float*)d_in[5];
    const float* b_v = (const float*)d_in[6];
    const float* w_o = (const float*)d_in[7];
    const float* b_o = (const float*)d_in[8];

    short* x_bf   = (short*)d_ws;
    short* wq_bf  = x_bf  + MTOT * EMBED;
    short* wk_bf  = wq_bf + EMBED * EMBED;
    short* wv_bf  = wk_bf + EMBED * EMBED;
    short* wo_bf  = wv_bf + EMBED * EMBED;
    short* q_bf   = wo_bf + EMBED * EMBED;              // [b,h,s,d] (pre-scaled)
    short* k_bf   = q_bf  + BATCH * HEADS * SEQ * HDIM; // [b,h,s,d]
    short* v_bf   = k_bf  + BATCH * HEADS * SEQ * HDIM; // [b,h,d,s]
    short* att_bf = v_bf  + BATCH * HEADS * SEQ * HDIM; // [b,s,E]

    cvt_all<<<dim3(1024, 5), 256, 0, stream>>>(x, w_q, w_k, w_v, w_o,
                                               x_bf, wq_bf, wk_bf, wv_bf, wo_bf);

    gemm_qkv<<<dim3(MTOT / 128, EMBED / 128, 3), 256, 0, stream>>>(
        x_bf, wq_bf, wk_bf, wv_bf, b_q, b_k, b_v, q_bf, k_bf, v_bf);

    flash_attn<<<dim3(SEQ / 64, BATCH * HEADS), 256, 32768, stream>>>(
        q_bf, k_bf, v_bf, att_bf);

    gemm_out<<<dim3(MTOT / 64, EMBED / 64), 256, 0, stream>>>(
        att_bf, wo_bf, b_o, (float*)d_out);
}

// Round 14
// 150.533 us; speedup vs baseline: 1.0760x; 1.0157x over previous
//
#include <hip/hip_runtime.h>
#include <math.h>

#define EMBED 768
#define HEADS 12
#define HDIM 64
#define BATCH 2
#define SEQ 2048
#define MTOT (BATCH*SEQ)   // 4096

typedef short s8v __attribute__((ext_vector_type(8)));
typedef short s4v __attribute__((ext_vector_type(4)));
typedef float f4v __attribute__((ext_vector_type(4)));

__device__ __forceinline__ short f2bf(float f) {
    union { float f; unsigned u; } v; v.f = f;
    unsigned r = v.u + 0x7FFFu + ((v.u >> 16) & 1u);
    return (short)(r >> 16);
}

// pack two floats -> two bf16 in one dword (manual; used in GEMM epilogue)
__device__ __forceinline__ unsigned pk2bf(float a, float b) {
    union { float f; unsigned u; } x, y; x.f = a; y.f = b;
    return ((y.u + 0x8000u) & 0xFFFF0000u) | ((x.u + 0x8000u) >> 16);
}

// HW packed convert: D.lo = bf16(a), D.hi = bf16(b), RNE
__device__ __forceinline__ unsigned cvtpk(float a, float b) {
    unsigned r;
    asm("v_cvt_pk_bf16_f32 %0, %1, %2" : "=v"(r) : "v"(a), "v"(b));
    return r;
}

__device__ __forceinline__ float fexp2(float x) {
#if __has_builtin(__builtin_amdgcn_exp2f)
    return __builtin_amdgcn_exp2f(x);
#else
    return exp2f(x);
#endif
}

// async global->LDS, 16B/lane; lds base wave-uniform, lane scatter on GLOBAL side ok
__device__ __forceinline__ void gll16(const short* g, short* l) {
    __builtin_amdgcn_global_load_lds((const __attribute__((address_space(1))) void*)g,
                                     (__attribute__((address_space(3))) void*)l, 16, 0, 0);
}

// ---------------- fp32 -> bf16 converts ----------------
__global__ __launch_bounds__(256) void cvt_all(
        const float* __restrict__ x,  const float* __restrict__ wq,
        const float* __restrict__ wk, const float* __restrict__ wv,
        const float* __restrict__ wo,
        short* __restrict__ xb, short* __restrict__ wqb, short* __restrict__ wkb,
        short* __restrict__ wvb, short* __restrict__ wob) {
    const int seg = blockIdx.y;
    const float* src; short* dst; int n4;
    if      (seg == 0) { src = x;  dst = xb;  n4 = MTOT * EMBED / 4; }
    else if (seg == 1) { src = wq; dst = wqb; n4 = EMBED * EMBED / 4; }
    else if (seg == 2) { src = wk; dst = wkb; n4 = EMBED * EMBED / 4; }
    else if (seg == 3) { src = wv; dst = wvb; n4 = EMBED * EMBED / 4; }
    else               { src = wo; dst = wob; n4 = EMBED * EMBED / 4; }
    for (int i = blockIdx.x * 256 + threadIdx.x; i < n4; i += gridDim.x * 256) {
        float4 f = ((const float4*)src)[i];
        short4 o;
        o.x = f2bf(f.x); o.y = f2bf(f.y); o.z = f2bf(f.z); o.w = f2bf(f.w);
        ((short4*)dst)[i] = o;
    }
}

// ---------------- fused QKV GEMM (BM=128, BN=96, BK=64, XOR-swizzled LDS) -----------
// C[m][n] = sum_k A[m][k]*W[n][k] + bias[n]
// mode(z): 0->Q [b,h,s,d] pre-scaled by 0.125*log2(e), 1->K [b,h,s,d], 2->V [b,h,d,s]
// r8-proven BK=64 drain structure (12 drains/block). BN 128->96 fixes the grid load
// imbalance: 32x8x3 = 768 blocks = EXACTLY 3/CU (was 576 = 2.25/CU: 64 CUs carried a
// 3rd block while 192 idled — runtime set by the loaded CUs). Max per-CU critical
// path drops 25%. r12 showed shrinking BM instead doubles drain events (+9us) — BN
// keeps drains/block constant. W restage 8x vs 6x; W (1.2MB) is L2-resident.
// Swizzle: chunk c of row r at slot c^(r&7); reads XOR lr&7 (row&7==lr&7 holds:
// 64*(wid>>1), 48*(wid&1), 16*mi/ni all == 0 mod 8).
__global__ __launch_bounds__(256, 4) void gemm_qkv(const short* __restrict__ A,
        const short* __restrict__ Wq, const short* __restrict__ Wk, const short* __restrict__ Wv,
        const float* __restrict__ bq, const float* __restrict__ bk, const float* __restrict__ bv,
        short* __restrict__ Qo, short* __restrict__ Ko, short* __restrict__ Vo) {
    const int mode = blockIdx.z;
    const short* W    = (mode == 0) ? Wq : (mode == 1) ? Wk : Wv;
    const float* bias = (mode == 0) ? bq : (mode == 1) ? bk : bv;
    // fold softmax scale (1/8) and log2(e) into Q so flash needs no fmaf on scores
    const float qs = (mode == 0) ? (0.125f * 1.44269504f) : 1.0f;

    __shared__ short As[128 * 64];   // 16 KB, rows of 128 B, XOR-swizzled
    __shared__ short Ws[96 * 64];    // 12 KB

    const int tid = threadIdx.x;
    const int lane = tid & 63, wid = tid >> 6;
    const int quad = lane >> 4, lr = lane & 15;
    const int m0 = blockIdx.x * 128, n0 = blockIdx.y * 96;
    const int wm = (wid >> 1) * 64, wn = (wid & 1) * 48;

    const int srow  = lane >> 3;                 // row within 8-row staging group
    const int sslot = (lane & 7) ^ srow;         // source chunk for XOR swizzle

    f4v acc[4][3];
    for (int a = 0; a < 4; a++)
        for (int b = 0; b < 3; b++)
            for (int i = 0; i < 4; i++) acc[a][b][i] = 0.f;

    for (int k0 = 0; k0 < EMBED; k0 += 64) {
        // stage A[128][64] (wave: rows wid*32..+32) + W[96][64] (wave: rows wid*24..+24)
#pragma unroll
        for (int i = 0; i < 4; i++) {
            const int r0 = wid * 32 + i * 8;
            gll16(&A[(long)(m0 + r0 + srow) * EMBED + k0 + sslot * 8], &As[r0 * 64]);
        }
#pragma unroll
        for (int i = 0; i < 3; i++) {
            const int r0 = wid * 24 + i * 8;
            gll16(&W[(long)(n0 + r0 + srow) * EMBED + k0 + sslot * 8], &Ws[r0 * 64]);
        }
        __syncthreads();

#pragma unroll
        for (int kk = 0; kk < 2; kk++) {
            s8v af[4], bf[3];
            for (int mi = 0; mi < 4; mi++)
                af[mi] = *(const s8v*)&As[(wm + mi * 16 + lr) * 64 + (((kk * 4 + quad) ^ (lr & 7)) * 8)];
            for (int ni = 0; ni < 3; ni++)
                bf[ni] = *(const s8v*)&Ws[(wn + ni * 16 + lr) * 64 + (((kk * 4 + quad) ^ (lr & 7)) * 8)];
            for (int mi = 0; mi < 4; mi++)
                for (int ni = 0; ni < 3; ni++)
                    acc[mi][ni] = __builtin_amdgcn_mfma_f32_16x16x32_bf16(af[mi], bf[ni], acc[mi][ni], 0, 0, 0);
        }
        __syncthreads();
    }

    if (mode == 2) {
        for (int mi = 0; mi < 4; mi++) {
            int srow2 = m0 + wm + mi * 16 + quad * 4;
            int b = srow2 >> 11, s = srow2 & 2047;
            for (int ni = 0; ni < 3; ni++) {
                int n = n0 + wn + ni * 16 + lr;
                int h = n >> 6, d = n & 63;
                float bb = bias[n];
                uint2 pk;
                pk.x = pk2bf(acc[mi][ni][0] + bb, acc[mi][ni][1] + bb);
                pk.y = pk2bf(acc[mi][ni][2] + bb, acc[mi][ni][3] + bb);
                *(uint2*)&Vo[(((long)(b * HEADS + h) * HDIM + d) * SEQ) + s] = pk;
            }
        }
    } else {
        short* Out = (mode == 0) ? Qo : Ko;
        for (int mi = 0; mi < 4; mi++) {
            for (int ni = 0; ni < 3; ni++) {
                int n = n0 + wn + ni * 16 + lr;
                int h = n >> 6, d = n & 63;
                float bb = bias[n];
                for (int i = 0; i < 4; i++) {
                    int m = m0 + wm + mi * 16 + quad * 4 + i;
                    int b = m >> 11, s = m & 2047;
                    Out[(((long)(b * HEADS + h) * SEQ + s) * HDIM) + d] =
                        f2bf((acc[mi][ni][i] + bb) * qs);
                }
            }
        }
    }
}

// ---------------- output projection GEMM (BM=64, BN=64, BK=64, XOR-swizzled) --------
// r13-proven (-2.8us vs BM=128/BN=64): 768 blocks = exactly 3/CU, even load.
__global__ __launch_bounds__(256, 4) void gemm_out(const short* __restrict__ A,
        const short* __restrict__ W, const float* __restrict__ bias,
        float* __restrict__ Out) {
    __shared__ short As[64 * 64];    // 8 KB
    __shared__ short Ws[64 * 64];    // 8 KB

    const int tid = threadIdx.x;
    const int lane = tid & 63, wid = tid >> 6;
    const int quad = lane >> 4, lr = lane & 15;
    const int m0 = blockIdx.x * 64, n0 = blockIdx.y * 64;
    const int wm = (wid >> 1) * 32, wn = (wid & 1) * 32;

    const int srow  = lane >> 3;
    const int sslot = (lane & 7) ^ srow;

    f4v acc[2][2];
    for (int a = 0; a < 2; a++)
        for (int b = 0; b < 2; b++)
            for (int i = 0; i < 4; i++) acc[a][b][i] = 0.f;

    for (int k0 = 0; k0 < EMBED; k0 += 64) {
#pragma unroll
        for (int i = 0; i < 2; i++) {
            const int r0 = wid * 16 + i * 8;
            gll16(&A[(long)(m0 + r0 + srow) * EMBED + k0 + sslot * 8], &As[r0 * 64]);
            gll16(&W[(long)(n0 + r0 + srow) * EMBED + k0 + sslot * 8], &Ws[r0 * 64]);
        }
        __syncthreads();

#pragma unroll
        for (int kk = 0; kk < 2; kk++) {
            s8v af[2], bf[2];
            for (int mi = 0; mi < 2; mi++)
                af[mi] = *(const s8v*)&As[(wm + mi * 16 + lr) * 64 + (((kk * 4 + quad) ^ (lr & 7)) * 8)];
            for (int ni = 0; ni < 2; ni++)
                bf[ni] = *(const s8v*)&Ws[(wn + ni * 16 + lr) * 64 + (((kk * 4 + quad) ^ (lr & 7)) * 8)];
            for (int mi = 0; mi < 2; mi++)
                for (int ni = 0; ni < 2; ni++)
                    acc[mi][ni] = __builtin_amdgcn_mfma_f32_16x16x32_bf16(af[mi], bf[ni], acc[mi][ni], 0, 0, 0);
        }
        __syncthreads();
    }

    for (int mi = 0; mi < 2; mi++)
        for (int ni = 0; ni < 2; ni++)
            for (int i = 0; i < 4; i++) {
                int m = m0 + wm + mi * 16 + quad * 4 + i;
                int n = n0 + wn + ni * 16 + lr;
                Out[(long)m * EMBED + n] = acc[mi][ni][i] + bias[n];
            }
}

// ---------------- flash attention: q-split waves, KVBLK=64, K+V dbuf, 32KB LDS ------
// BYTE-IDENTICAL to the r8-proven version (46.3 us). The inner compute chain is
// FROZEN: r5/r6 (unroll), r10 (K-from-global) — semantically-sound transforms of the
// data path feeding the MFMA+cvtpk chain miscompile on this toolchain. Sync-scheme
// changes (r9) pass but don't help: flash is not staging-bound (r8 == r9 counters).
__global__ __launch_bounds__(256, 4) void flash_attn(const short* __restrict__ Q,
        const short* __restrict__ K, const short* __restrict__ Vt,
        short* __restrict__ Out) {
    extern __shared__ char pool[];
    short* Ks = (short*)pool;             // [2][64*64] shorts = 16 KB
    short* Vs = Ks + 2 * 64 * 64;         // [2][64*64] shorts = 16 KB

    const int bh = blockIdx.y;
    const int tid = threadIdx.x, lane = tid & 63, wid = tid >> 6;
    const int quad = lane >> 4, lr = lane & 15;
    const int q0 = blockIdx.x * 64;
    const int qw = q0 + wid * 16;         // wave's q base (exclusive ownership)

    const short* Qb = Q  + (long)bh * SEQ * HDIM;
    const short* Kb = K  + (long)bh * SEQ * HDIM;
    const short* Vb = Vt + (long)bh * HDIM * SEQ;

    // Q fragments (B-operand: lane lr = q row, k = d = hh*32 + quad*8 + j)
    s8v qf[2];
#pragma unroll
    for (int hh = 0; hh < 2; hh++)
        qf[hh] = *(const s8v*)&Qb[(qw + lr) * HDIM + hh * 32 + quad * 8];

    f4v o[4];
#pragma unroll
    for (int dt = 0; dt < 4; dt++)
        for (int i = 0; i < 4; i++) o[dt][i] = 0.f;
    float lsum = 0.f;

    // p = exp(s/8 - 16) = exp2(s_scaled + SB2); scale folded into Q upstream
    const float SB2 = -16.0f * 1.44269504f;

    const int srow  = lane >> 3;                 // row within 8-row staging group
    const int sslot = (lane & 7) ^ srow;         // source chunk for XOR swizzle

    // prologue: K/V tile 0 -> buffers 0 (each wave stages 2 K-rows-groups + 2 V)
#pragma unroll
    for (int i = 0; i < 2; i++) {
        const int r0 = wid * 16 + i * 8;
        gll16(&Kb[(long)(r0 + srow) * HDIM + sslot * 8], &Ks[r0 * 64]);
        gll16(&Vb[(long)(r0 + srow) * SEQ + sslot * 8], &Vs[r0 * 64]);
    }
    __syncthreads();

    for (int r = 0; r < 32; r++) {
        const int cur = r & 1;
        const short* Kc = Ks + cur * (64 * 64);
        const short* Vc = Vs + cur * (64 * 64);
        short* Kn = Ks + (cur ^ 1) * (64 * 64);
        short* Vn = Vs + (cur ^ 1) * (64 * 64);

        // ---- prefetch tile r+1 into the other buffers (4 loads/wave) ----
        if (r < 31) {
            const int kn0 = (r + 1) * 64;
#pragma unroll
            for (int i = 0; i < 2; i++) {
                const int r0 = wid * 16 + i * 8;
                gll16(&Kb[(long)(kn0 + r0 + srow) * HDIM + sslot * 8], &Kn[r0 * 64]);
                gll16(&Vb[(long)(r0 + srow) * SEQ + kn0 + sslot * 8], &Vn[r0 * 64]);
            }
        }

        // ---- QK^T + softmax: 16 q rows x 64 keys ----
        // lane (quad,lr) gets p[q=qw+lr][key = nt*16 + quad*4 + i]
        unsigned pw[2][4];    // [k-half h][4 dwords] -> A-fragment, slot (quad,j):
                              // key = h*32 + (j>>2)*16 + quad*4 + (j&3)
#pragma unroll
        for (int nt = 0; nt < 4; nt++) {
            const int row = nt * 16 + lr;
            s8v kf0 = *(const s8v*)&Kc[row * 64 + ((quad ^ (lr & 7)) * 8)];
            s8v kf1 = *(const s8v*)&Kc[row * 64 + (((4 + quad) ^ (lr & 7)) * 8)];
            f4v s = {SB2, SB2, SB2, SB2};
            s = __builtin_amdgcn_mfma_f32_16x16x32_bf16(kf0, qf[0], s, 0, 0, 0);
            s = __builtin_amdgcn_mfma_f32_16x16x32_bf16(kf1, qf[1], s, 0, 0, 0);
            float p0 = fexp2(s[0]);
            float p1 = fexp2(s[1]);
            float p2 = fexp2(s[2]);
            float p3 = fexp2(s[3]);
            lsum += (p0 + p1) + (p2 + p3);
            pw[nt >> 1][(nt & 1) * 2]     = cvtpk(p0, p1);
            pw[nt >> 1][(nt & 1) * 2 + 1] = cvtpk(p2, p3);
        }

        // ---- PV: o[16 q][64 d] += P[16 q][64 k] * V[64 k][64 d] ----
#pragma unroll
        for (int h = 0; h < 2; h++) {
            s8v pf = *(s8v*)&pw[h][0];
            const int cb0 = h * 4 + (quad >> 1);      // chunk of keys h*32+quad*4..
#pragma unroll
            for (int dt = 0; dt < 4; dt++) {
                const int d = dt * 16 + lr;
                const int c0 = cb0 ^ (lr & 7);
                const int c1 = (cb0 + 2) ^ (lr & 7);
                s4v v0 = *(const s4v*)&Vc[d * 64 + c0 * 8 + (quad & 1) * 4];
                s4v v1 = *(const s4v*)&Vc[d * 64 + c1 * 8 + (quad & 1) * 4];
                s8v vf = __builtin_shufflevector(v0, v1, 0, 1, 2, 3, 4, 5, 6, 7);
                o[dt] = __builtin_amdgcn_mfma_f32_16x16x32_bf16(pf, vf, o[dt], 0, 0, 0);
            }
        }
        __syncthreads();   // drains prefetch (vmcnt0) + all LDS reads (lgkmcnt0)
    }

    // ---- epilogue: reduce lsum across quads, redistribute, scale, store ----
    lsum += __shfl_xor(lsum, 16);
    lsum += __shfl_xor(lsum, 32);      // lane L now holds full sum for q-row (L&15)
    float linv[4];
#pragma unroll
    for (int i = 0; i < 4; i++)
        linv[i] = 1.0f / __shfl(lsum, quad * 4 + i);

    const int b = bh / HEADS, h = bh % HEADS;
#pragma unroll
    for (int dt = 0; dt < 4; dt++)
#pragma unroll
        for (int i = 0; i < 4; i++) {
            const int q = qw + quad * 4 + i;
            Out[((long)(b * SEQ + q)) * EMBED + h * HDIM + dt * 16 + lr] =
                f2bf(o[dt][i] * linv[i]);
        }
}

extern "C" void kernel_launch(void* const* d_in, const int* in_sizes, int n_in,
                              void* d_out, int out_size, void* d_ws, size_t ws_size,
                              hipStream_t stream) {
    const float* x   = (const float*)d_in[0];
    const float* w_q = (const float*)d_in[1];
    const float* b_q = (const float*)d_in[2];
    const float* w_k = (const float*)d_in[3];
    const float* b_k = (const float*)d_in[4];
    const float* w_v = (const float*)d_in[5];
    const float* b_v = (const float*)d_in[6];
    const float* w_o = (const float*)d_in[7];
    const float* b_o = (const float*)d_in[8];

    short* x_bf   = (short*)d_ws;
    short* wq_bf  = x_bf  + MTOT * EMBED;
    short* wk_bf  = wq_bf + EMBED * EMBED;
    short* wv_bf  = wk_bf + EMBED * EMBED;
    short* wo_bf  = wv_bf + EMBED * EMBED;
    short* q_bf   = wo_bf + EMBED * EMBED;              // [b,h,s,d] (pre-scaled)
    short* k_bf   = q_bf  + BATCH * HEADS * SEQ * HDIM; // [b,h,s,d]
    short* v_bf   = k_bf  + BATCH * HEADS * SEQ * HDIM; // [b,h,d,s]
    short* att_bf = v_bf  + BATCH * HEADS * SEQ * HDIM; // [b,s,E]

    cvt_all<<<dim3(1024, 5), 256, 0, stream>>>(x, w_q, w_k, w_v, w_o,
                                               x_bf, wq_bf, wk_bf, wv_bf, wo_bf);

    gemm_qkv<<<dim3(MTOT / 128, EMBED / 96, 3), 256, 0, stream>>>(
        x_bf, wq_bf, wk_bf, wv_bf, b_q, b_k, b_v, q_bf, k_bf, v_bf);

    flash_attn<<<dim3(SEQ / 64, BATCH * HEADS), 256, 32768, stream>>>(
        q_bf, k_bf, v_bf, att_bf);

    gemm_out<<<dim3(MTOT / 64, EMBED / 64), 256, 0, stream>>>(
        att_bf, wo_bf, b_o, (float*)d_out);
}